// Round 1
// baseline (44.874 us; speedup 1.0000x reference)
//
#include <hip/hip_runtime.h>
#include <hip/hip_bf16.h>
#include <math.h>

#define Bn   16
#define T1n  256
#define T2n  256
#define Dn   256
#define MPn  32

typedef __attribute__((ext_vector_type(8))) short short8;
typedef __attribute__((ext_vector_type(4))) float f32x4;
typedef __attribute__((ext_vector_type(4))) float float4v;

__device__ inline short f2b(float f) {
  __hip_bfloat16 h = __float2bfloat16(f);
  return __builtin_bit_cast(short, h);
}

// swizzled 16B-chunk index within a [64 row][256 d] bf16 tile.
// row in [0,64), d8 (16B unit along d) in [0,32).
// XOR of row&7 into the chunk bits spreads the stride-512B column reads
// across 8 distinct 16B slots -> 2-way bank aliasing (free, m136).
__device__ inline int swz_chunk(int row, int d8) {
  return row * 32 + (d8 ^ (row & 7));
}

__global__ __launch_bounds__(256, 2)
void mp_match_kernel(const float* __restrict__ lt,
                     const float* __restrict__ rt,
                     const float* __restrict__ kern,
                     float* __restrict__ out) {
  __shared__ short lds_rt[64 * 256];   // rtk tile, bf16 bits
  __shared__ short lds_lt[64 * 256];   // lt chunk, bf16 bits
  __shared__ float kvec[Dn];
  __shared__ float red[2][2][2][16];   // [wi][wj][sub][col]

  const int bid  = blockIdx.x;
  const int m    = bid & (MPn - 1);
  const int jblk = (bid >> 5) & 3;
  const int b    = bid >> 7;
  const int j0   = jblk * 64;

  const int tid  = threadIdx.x;
  const int lane = tid & 63;
  const int w    = tid >> 6;
  const int wi   = w >> 1;   // i-half of the 64-row chunk
  const int wj   = w & 1;    // j-half of the 64-col tile

  // 1) kernel row m -> LDS (f32)
  kvec[tid] = kern[m * Dn + tid];
  __syncthreads();

  // 2) stage rtk = bf16(rt * k[m])  [64 j][256 d]
  {
    const float* rbase = rt + ((size_t)b * T2n + j0) * Dn;
    #pragma unroll
    for (int rep = 0; rep < 8; ++rep) {
      int chunk = rep * 256 + tid;     // 0..2047
      int row = chunk >> 5;
      int d8  = chunk & 31;
      const float4v* s = reinterpret_cast<const float4v*>(rbase + row * Dn + d8 * 8);
      float4v f0 = s[0], f1 = s[1];
      const float* kv = &kvec[d8 * 8];
      short8 v;
      v[0] = f2b(f0.x * kv[0]); v[1] = f2b(f0.y * kv[1]);
      v[2] = f2b(f0.z * kv[2]); v[3] = f2b(f0.w * kv[3]);
      v[4] = f2b(f1.x * kv[4]); v[5] = f2b(f1.y * kv[5]);
      v[6] = f2b(f1.z * kv[6]); v[7] = f2b(f1.w * kv[7]);
      *reinterpret_cast<short8*>(&lds_rt[swz_chunk(row, d8) * 8]) = v;
    }
  }
  __syncthreads();

  // 3) hoist B fragments (2 j-subtiles x 8 k-steps) into registers
  short8 bfrag[2][8];
  {
    const int bl = lane & 15, hl = lane >> 4;
    #pragma unroll
    for (int sub = 0; sub < 2; ++sub) {
      int brow = wj * 32 + sub * 16 + bl;
      #pragma unroll
      for (int kk = 0; kk < 8; ++kk) {
        int d8 = kk * 4 + hl;
        bfrag[sub][kk] = *reinterpret_cast<const short8*>(&lds_rt[swz_chunk(brow, d8) * 8]);
      }
    }
  }

  float jmax0 = -1e30f, jmax1 = -1e30f;
  const int al = lane & 15, hl = lane >> 4;

  // 4) loop over lt chunks of 64 i-rows
  for (int ic = 0; ic < 4; ++ic) {
    const float* lbase = lt + ((size_t)b * T1n + ic * 64) * Dn;
    #pragma unroll
    for (int rep = 0; rep < 8; ++rep) {
      int chunk = rep * 256 + tid;
      int row = chunk >> 5;
      int d8  = chunk & 31;
      const float4v* s = reinterpret_cast<const float4v*>(lbase + row * Dn + d8 * 8);
      float4v f0 = s[0], f1 = s[1];
      short8 v;
      v[0] = f2b(f0.x); v[1] = f2b(f0.y); v[2] = f2b(f0.z); v[3] = f2b(f0.w);
      v[4] = f2b(f1.x); v[5] = f2b(f1.y); v[6] = f2b(f1.z); v[7] = f2b(f1.w);
      *reinterpret_cast<short8*>(&lds_lt[swz_chunk(row, d8) * 8]) = v;
    }
    __syncthreads();

    #pragma unroll
    for (int it = 0; it < 2; ++it) {
      int arow = wi * 32 + it * 16 + al;
      f32x4 acc0 = {0.f, 0.f, 0.f, 0.f};
      f32x4 acc1 = {0.f, 0.f, 0.f, 0.f};
      #pragma unroll
      for (int kk = 0; kk < 8; ++kk) {
        int d8 = kk * 4 + hl;
        short8 a = *reinterpret_cast<const short8*>(&lds_lt[swz_chunk(arow, d8) * 8]);
        acc0 = __builtin_amdgcn_mfma_f32_16x16x32_bf16(a, bfrag[0][kk], acc0, 0, 0, 0);
        acc1 = __builtin_amdgcn_mfma_f32_16x16x32_bf16(a, bfrag[1][kk], acc1, 0, 0, 0);
      }
      // column-max over this 16-row i-subtile (row perm under max is irrelevant)
      float c0 = fmaxf(fmaxf(acc0.x, acc0.y), fmaxf(acc0.z, acc0.w));
      float c1 = fmaxf(fmaxf(acc1.x, acc1.y), fmaxf(acc1.z, acc1.w));
      c0 = fmaxf(c0, __shfl_xor(c0, 16));
      c0 = fmaxf(c0, __shfl_xor(c0, 32));
      c1 = fmaxf(c1, __shfl_xor(c1, 16));
      c1 = fmaxf(c1, __shfl_xor(c1, 32));
      jmax0 = fmaxf(jmax0, c0);
      jmax1 = fmaxf(jmax1, c1);
    }
    __syncthreads();
  }

  // 5) combine the two i-half waves sharing each j column, tanh, store
  if (lane < 16) {
    red[wi][wj][0][lane] = jmax0;
    red[wi][wj][1][lane] = jmax1;
  }
  __syncthreads();
  if (tid < 64) {
    int col = tid & 15;
    int sub = (tid >> 4) & 1;
    int wjj = tid >> 5;
    float v = fmaxf(red[0][wjj][sub][col], red[1][wjj][sub][col]);
    int j = j0 + wjj * 32 + sub * 16 + col;
    out[((size_t)b * T2n + j) * MPn + m] = tanhf(v);
  }
}

extern "C" void kernel_launch(void* const* d_in, const int* in_sizes, int n_in,
                              void* d_out, int out_size, void* d_ws, size_t ws_size,
                              hipStream_t stream) {
  const float* lt   = (const float*)d_in[0];
  const float* rt   = (const float*)d_in[1];
  const float* kern = (const float*)d_in[2];
  float* out = (float*)d_out;

  dim3 grid(Bn * MPn * (T2n / 64));   // 2048 blocks: b[10:7] jblk[6:5] m[4:0]
  dim3 block(256);
  mp_match_kernel<<<grid, block, 0, stream>>>(lt, rt, kern, out);
}

// Round 2
// 24.441 us; speedup vs baseline: 1.8360x; 1.8360x over previous
//
#include <hip/hip_runtime.h>
#include <hip/hip_bf16.h>
#include <math.h>

#define Bn   16
#define T1n  256
#define T2n  256
#define Dn   256
#define MPn  32

typedef __attribute__((ext_vector_type(8))) short short8;
typedef __attribute__((ext_vector_type(4))) float f32x4;

__device__ inline short f2b(float f) {
  __hip_bfloat16 h = __float2bfloat16(f);
  return __builtin_bit_cast(short, h);
}
__device__ inline float b2f(short s) {
  unsigned int u = ((unsigned int)(unsigned short)s) << 16;
  return __builtin_bit_cast(float, u);
}

// swizzled 16B-chunk index within a [64 row][256 d] bf16 tile.
// XOR of row&7 spreads stride-512B column reads across 8 16B slots ->
// uniform 8-accesses/bank for wave64 ds_read_b128 (minimum, conflict-free).
__device__ inline int swz_chunk(int row, int d8) {
  return row * 32 + (d8 ^ (row & 7));
}

__global__ __launch_bounds__(256, 2)
void mp_match_kernel(const float* __restrict__ lt,
                     const float* __restrict__ rt,
                     const float* __restrict__ kern,
                     float* __restrict__ out) {
  __shared__ short lds_rt[64 * 256];   // raw rt tile, bf16 bits, swizzled
  __shared__ short lds_lt[64 * 256];   // lt chunk, bf16 bits, swizzled

  // bid = ((b>>3)*32 + widx)*8 + (b&7): co-locates each b's 32 blocks on
  // one XCD (assuming XCD = bid%8 round-robin; perf-only, correct anyway).
  const int bid  = blockIdx.x;
  const int xcd  = bid & 7;
  const int q    = bid >> 3;
  const int widx = q & 31;
  const int b    = ((q >> 5) << 3) | xcd;
  const int jblk = widx & 3;
  const int mg   = widx >> 2;          // 8 m-groups of 4
  const int j0   = jblk * 64;

  const int tid  = threadIdx.x;
  const int lane = tid & 63;
  const int w    = tid >> 6;           // wave -> its own m
  const int m    = mg * 4 + w;

  const int bl = lane & 15;            // row-within-16 for A/B frags
  const int hl = lane >> 4;            // k-subchunk selector

  // ---- stage raw rt tile [64 j][256 d] -> bf16 LDS (swizzled) ----
  {
    const float* rbase = rt + ((size_t)b * T2n + j0) * Dn;
    #pragma unroll
    for (int rep = 0; rep < 8; ++rep) {
      int chunk = rep * 256 + tid;           // 0..2047
      int row = chunk >> 5, c = chunk & 31;
      const f32x4* s = reinterpret_cast<const f32x4*>(rbase + row * Dn + c * 8);
      f32x4 f0 = s[0], f1 = s[1];
      short8 v;
      v[0] = f2b(f0.x); v[1] = f2b(f0.y); v[2] = f2b(f0.z); v[3] = f2b(f0.w);
      v[4] = f2b(f1.x); v[5] = f2b(f1.y); v[6] = f2b(f1.z); v[7] = f2b(f1.w);
      *reinterpret_cast<short8*>(&lds_rt[swz_chunk(row, c) * 8]) = v;
    }
  }
  __syncthreads();

  // ---- load B fragments, scale by k[m] once per block (in registers) ----
  short8 bsc[4][8];                    // [j-subtile][k-step], 128 VGPR
  {
    const float* kbase = kern + (size_t)m * Dn;
    #pragma unroll
    for (int kk = 0; kk < 8; ++kk) {
      int d8 = kk * 4 + hl;
      const f32x4* kp = reinterpret_cast<const f32x4*>(kbase + d8 * 8);
      f32x4 k0 = kp[0], k1 = kp[1];
      #pragma unroll
      for (int sub = 0; sub < 4; ++sub) {
        int brow = sub * 16 + bl;
        short8 r = *reinterpret_cast<const short8*>(&lds_rt[swz_chunk(brow, d8) * 8]);
        short8 v;
        v[0] = f2b(b2f(r[0]) * k0.x); v[1] = f2b(b2f(r[1]) * k0.y);
        v[2] = f2b(b2f(r[2]) * k0.z); v[3] = f2b(b2f(r[3]) * k0.w);
        v[4] = f2b(b2f(r[4]) * k1.x); v[5] = f2b(b2f(r[5]) * k1.y);
        v[6] = f2b(b2f(r[6]) * k1.z); v[7] = f2b(b2f(r[7]) * k1.w);
        bsc[sub][kk] = v;
      }
    }
  }

  float jmax0 = -1e30f, jmax1 = -1e30f, jmax2 = -1e30f, jmax3 = -1e30f;

  // ---- loop over lt chunks of 64 i-rows; every wave computes all i for its m ----
  for (int ic = 0; ic < 4; ++ic) {
    if (ic) __syncthreads();           // prev compute done before overwrite
    const float* lbase = lt + ((size_t)b * T1n + ic * 64) * Dn;
    #pragma unroll
    for (int rep = 0; rep < 8; ++rep) {
      int chunk = rep * 256 + tid;
      int row = chunk >> 5, c = chunk & 31;
      const f32x4* s = reinterpret_cast<const f32x4*>(lbase + row * Dn + c * 8);
      f32x4 f0 = s[0], f1 = s[1];
      short8 v;
      v[0] = f2b(f0.x); v[1] = f2b(f0.y); v[2] = f2b(f0.z); v[3] = f2b(f0.w);
      v[4] = f2b(f1.x); v[5] = f2b(f1.y); v[6] = f2b(f1.z); v[7] = f2b(f1.w);
      *reinterpret_cast<short8*>(&lds_lt[swz_chunk(row, c) * 8]) = v;
    }
    __syncthreads();

    #pragma unroll
    for (int it = 0; it < 4; ++it) {
      f32x4 acc0 = {0.f,0.f,0.f,0.f}, acc1 = {0.f,0.f,0.f,0.f};
      f32x4 acc2 = {0.f,0.f,0.f,0.f}, acc3 = {0.f,0.f,0.f,0.f};
      int arow = it * 16 + bl;
      #pragma unroll
      for (int kk = 0; kk < 8; ++kk) {
        int d8 = kk * 4 + hl;
        short8 a = *reinterpret_cast<const short8*>(&lds_lt[swz_chunk(arow, d8) * 8]);
        acc0 = __builtin_amdgcn_mfma_f32_16x16x32_bf16(a, bsc[0][kk], acc0, 0, 0, 0);
        acc1 = __builtin_amdgcn_mfma_f32_16x16x32_bf16(a, bsc[1][kk], acc1, 0, 0, 0);
        acc2 = __builtin_amdgcn_mfma_f32_16x16x32_bf16(a, bsc[2][kk], acc2, 0, 0, 0);
        acc3 = __builtin_amdgcn_mfma_f32_16x16x32_bf16(a, bsc[3][kk], acc3, 0, 0, 0);
      }
      // fold 4 accumulator rows per lane into per-lane running col-max
      jmax0 = fmaxf(jmax0, fmaxf(fmaxf(acc0.x, acc0.y), fmaxf(acc0.z, acc0.w)));
      jmax1 = fmaxf(jmax1, fmaxf(fmaxf(acc1.x, acc1.y), fmaxf(acc1.z, acc1.w)));
      jmax2 = fmaxf(jmax2, fmaxf(fmaxf(acc2.x, acc2.y), fmaxf(acc2.z, acc2.w)));
      jmax3 = fmaxf(jmax3, fmaxf(fmaxf(acc3.x, acc3.y), fmaxf(acc3.z, acc3.w)));
    }
  }

  // ---- cross-lane max over the 4 row-groups (lane>>4), tanh, store ----
  jmax0 = fmaxf(jmax0, __shfl_xor(jmax0, 16));
  jmax0 = fmaxf(jmax0, __shfl_xor(jmax0, 32));
  jmax1 = fmaxf(jmax1, __shfl_xor(jmax1, 16));
  jmax1 = fmaxf(jmax1, __shfl_xor(jmax1, 32));
  jmax2 = fmaxf(jmax2, __shfl_xor(jmax2, 16));
  jmax2 = fmaxf(jmax2, __shfl_xor(jmax2, 32));
  jmax3 = fmaxf(jmax3, __shfl_xor(jmax3, 16));
  jmax3 = fmaxf(jmax3, __shfl_xor(jmax3, 32));

  if (lane < 16) {
    out[((size_t)b * T2n + (j0 +  0 + lane)) * MPn + m] = tanhf(jmax0);
    out[((size_t)b * T2n + (j0 + 16 + lane)) * MPn + m] = tanhf(jmax1);
    out[((size_t)b * T2n + (j0 + 32 + lane)) * MPn + m] = tanhf(jmax2);
    out[((size_t)b * T2n + (j0 + 48 + lane)) * MPn + m] = tanhf(jmax3);
  }
}

extern "C" void kernel_launch(void* const* d_in, const int* in_sizes, int n_in,
                              void* d_out, int out_size, void* d_ws, size_t ws_size,
                              hipStream_t stream) {
  const float* lt   = (const float*)d_in[0];
  const float* rt   = (const float*)d_in[1];
  const float* kern = (const float*)d_in[2];
  float* out = (float*)d_out;

  dim3 grid(Bn * 4 * (MPn / 4));   // 512 blocks: b(16) x jblk(4) x mgroup(8)
  dim3 block(256);                 // 4 waves, one m per wave
  mp_match_kernel<<<grid, block, 0, stream>>>(lt, rt, kern, out);
}